// Round 11
// baseline (232.834 us; speedup 1.0000x reference)
//
#include <hip/hip_runtime.h>

// Problem constants
#define B_  2
#define N_  20000
#define C_  256
#define K_  5000
#define M_  (B_ * K_)     // 10000
#define CAP_ 5376         // survivor capacity per batch
#define NBIN_ 2048
#define AST_ 264          // act LDS row stride (shorts): 16B-aligned
#define RT_  21           // CAP_/256 j-tiles
#define RCH_ 7            // rank chunk count
#define RCT_ 3            // tiles per rank chunk
#define MLPROWS_ 48       // rows per k_mlp6 block
#define MLPBLK_ 209       // ceil(10016/48) -> 209*48 = 10032 <= 10112 alloc

typedef __attribute__((ext_vector_type(8))) short bf16x8;
typedef __attribute__((ext_vector_type(4))) float f32x4;
typedef __attribute__((ext_vector_type(2))) unsigned long long ull2;

__device__ __forceinline__ unsigned short f2bf(float x) {
  unsigned u = __float_as_uint(x);
  return (unsigned short)((u + 0x7fffu + ((u >> 16) & 1u)) >> 16);
}
__device__ __forceinline__ float bf2f(unsigned short h) {
  return __uint_as_float(((unsigned)h) << 16);
}
__device__ __forceinline__ unsigned fkey(float f) {
  unsigned u = __float_as_uint(f);
  return (u & 0x80000000u) ? ~u : (u | 0x80000000u);
}
// monotone linear bin; only hist/compact CONSISTENCY matters (upward-closed set)
__device__ __forceinline__ int binof(float s) {
  int b = (int)(s * 2048.0f);
  return b < 0 ? 0 : (b > 2047 ? 2047 : b);
}
__device__ __forceinline__ bf16x8 as_bf(uint4 v) {
  union { uint4 u; bf16x8 b; } c; c.u = v; return c.b;
}

// ---------------------------------------------------------------------------
// K1: W f32 -> bf16 hi/lo split, PRE-PACKED into per-wave MFMA fragment order
// for the 8-wave k_mlp6:  Wp[l][w8][ks][oi2][lane][j]  (j=0..7 shorts)
// holding W[o = w*32 + oi*16 + (lane&15)][k = ks*32 + (lane>>4)*8 + j].
// Also zeros nc, cnt2, ticket.
__global__ __launch_bounds__(256) void k_prep(const float* __restrict__ W,
                                              unsigned short* __restrict__ Whi,
                                              unsigned short* __restrict__ Wlo,
                                              int* __restrict__ nc,
                                              int* __restrict__ cnt2,
                                              int* __restrict__ ticket) {
  const int u = blockIdx.x;
  const int t = threadIdx.x;
  if (u >= 192) {
    if (u == 234) {
      if (t < B_) nc[t] = 0;
      if (t >= 32 && t < 32 + B_ * RT_) ticket[t - 32] = 0;
      return;
    }
    const int i = (u - 192) * 256 + t;
    if (i < B_ * CAP_) cnt2[i] = 0;
    return;
  }
  const int idx = u * 256 + t;  // 0..49151 = [l][w][ks][oi][lane]
  const int lane = idx & 63;
  const int oi = (idx >> 6) & 1;
  const int ks = (idx >> 7) & 7;
  const int w = (idx >> 10) & 7;
  const int l = idx >> 13;
  const int o = w * 32 + oi * 16 + (lane & 15);
  const int k0 = ks * 32 + (lane >> 4) * 8;
  const float* src = W + ((size_t)(l * C_ + o)) * C_ + k0;
  float4 w0 = *(const float4*)&src[0];
  float4 w1 = *(const float4*)&src[4];
  const float wv[8] = {w0.x, w0.y, w0.z, w0.w, w1.x, w1.y, w1.z, w1.w};
  unsigned short hs[8], ls[8];
#pragma unroll
  for (int q = 0; q < 8; ++q) {
    hs[q] = f2bf(wv[q]);
    ls[q] = f2bf(__fsub_rn(wv[q], bf2f(hs[q])));
  }
  *(uint4*)&Whi[(size_t)idx * 8] = *(const uint4*)&hs[0];
  *(uint4*)&Wlo[(size_t)idx * 8] = *(const uint4*)&ls[0];
}

// ---------------------------------------------------------------------------
// K2: per-block LDS histogram + select threshold bin + compact survivors.
__global__ __launch_bounds__(256) void k_selcomp(const float* __restrict__ score,
                                                 int* __restrict__ nc,
                                                 unsigned long long* __restrict__ ck,
                                                 int* __restrict__ rnk) {
  const int b = blockIdx.y;
  const float* s = score + b * N_;
  __shared__ int h[NBIN_];
  __shared__ int chs[256];
  __shared__ int res[1];
  const int t = threadIdx.x;
  for (int i = t; i < NBIN_; i += 256) h[i] = 0;
  __syncthreads();
  for (int i = t; i < N_; i += 256) atomicAdd(&h[binof(s[i])], 1);
  __syncthreads();
  int sum = 0;
#pragma unroll
  for (int j = 0; j < 8; ++j) sum += h[t * 8 + j];
  chs[t] = sum;
  __syncthreads();
  for (int off = 1; off < 256; off <<= 1) {
    int v = chs[t] + ((t + off < 256) ? chs[t + off] : 0);
    __syncthreads();
    chs[t] = v;
    __syncthreads();
  }
  const int above = (t + 1 < 256) ? chs[t + 1] : 0;
  if (above < K_ && K_ <= chs[t]) {
    int acc = above;
    for (int i = 7; i >= 0; --i) {
      const int bin = t * 8 + i;
      if (acc + h[bin] >= K_) { res[0] = bin; break; }
      acc += h[bin];
    }
  }
  __syncthreads();
  const int selB = res[0];
  const int n = blockIdx.x * 256 + t;
  if (n < N_) {
    rnk[b * N_ + n] = K_;
    const float sv = s[n];
    if (binof(sv) >= selB) {
      const int pos = atomicAdd(&nc[b], 1);
      if (pos < CAP_)
        ck[b * CAP_ + pos] =
            ((unsigned long long)fkey(sv) << 32) | (unsigned)(N_ - 1 - n);
    }
  }
}

// ---------------------------------------------------------------------------
// K3: partial exact rank among survivors (chunked, 294 blocks) + FUSED
// scatter: the last chunk-block to finish a (b,jt) tile (ticket election)
// reads the final ranks for its own tile and scatters keep/rnk/boxK/maxiou.
__global__ __launch_bounds__(256) void k_rank2(const int* __restrict__ nc,
                                               const unsigned long long* __restrict__ ck,
                                               int* __restrict__ cnt2,
                                               int* __restrict__ ticket,
                                               const float* __restrict__ box,
                                               int* __restrict__ keep_i,
                                               float* __restrict__ out_keep,
                                               int* __restrict__ rnk,
                                               float* __restrict__ boxK,
                                               unsigned* __restrict__ maxiou) {
  const int b = blockIdx.z;
  const int jt = blockIdx.x;
  int S = nc[b]; if (S > CAP_) S = CAP_;
  __shared__ unsigned long long sk[256];
  __shared__ int amLast;
  const int t = threadIdx.x;
  const int j = jt * 256 + t;
  const unsigned long long* kb = ck + b * CAP_;
  const unsigned long long myk = (j < S) ? kb[j] : 0ULL;
  int c = 0;
  const int nt = (S + 255) >> 8;
  int t0 = blockIdx.y * RCT_, t1 = t0 + RCT_;
  if (t1 > nt) t1 = nt;
  for (int tt = t0; tt < t1; ++tt) {
    const int gi = tt * 256 + t;
    unsigned long long kk = (gi < S) ? kb[gi] : 0ULL;
    __syncthreads();
    sk[t] = kk;
    __syncthreads();
#pragma unroll 8
    for (int ii = 0; ii < 256; ii += 2) {
      ull2 v = *(const ull2*)&sk[ii];
      c += (int)(v.x > myk) + (int)(v.y > myk);
    }
  }
  if (j < S && c > 0) atomicAdd(&cnt2[b * CAP_ + j], c);
  // release partial counts, then elect the last block for this (b, jt)
  __threadfence();
  __syncthreads();
  if (t == 0) amLast = (atomicAdd(&ticket[b * RT_ + jt], 1) == RCH_ - 1);
  __syncthreads();
  if (!amLast) return;
  __threadfence();  // acquire: see all other blocks' cnt2 updates
  if (j >= S) return;
  const int cf = atomicAdd(&cnt2[b * CAP_ + j], 0);  // device-scope read
  if (cf >= K_) return;
  const int n = N_ - 1 - (int)(myk & 0xffffffffu);
  keep_i[b * K_ + cf] = n;
  out_keep[b * K_ + cf] = (float)n;
  rnk[b * N_ + n] = cf;
  const float* bb = box + (size_t)b * 4 * N_;
  float4 v;
  v.x = bb[n]; v.y = bb[N_ + n]; v.z = bb[2 * N_ + n]; v.w = bb[3 * N_ + n];
  ((float4*)boxK)[b * K_ + cf] = v;
  maxiou[b * K_ + cf] = 0u;
}

// ---------------------------------------------------------------------------
// K4: iou (420 triangular units) + gather/transpose/split (2504 units).
__global__ __launch_bounds__(256) void k_ioug(const float* __restrict__ boxK,
                                              unsigned* __restrict__ maxiou,
                                              const int* __restrict__ rnk,
                                              const float* __restrict__ feat,
                                              unsigned short* __restrict__ Xhi,
                                              unsigned short* __restrict__ Xlo) {
  __shared__ __align__(16) char arena[16640];
  const int u = blockIdx.x;
  const int t = threadIdx.x;
  if (u < 420) {
    const int b = u / 210;
    const int p = u % 210;
    int jt = 0;
    while ((jt + 1) * (jt + 2) / 2 <= p) ++jt;
    const int it = p - jt * (jt + 1) / 2;
    float* sx0 = (float*)arena;
    float* sy0 = sx0 + 256; float* sx1 = sy0 + 256;
    float* sy1 = sx1 + 256; float* sa = sy1 + 256;
    const int gi0 = it * 256;
    const int gl = gi0 + t;
    if (gl < K_) {
      float4 v = ((const float4*)boxK)[b * K_ + gl];
      sx0[t] = v.x; sy0[t] = v.y; sx1[t] = v.z; sy1[t] = v.w;
      sa[t] = __fmul_rn(__fsub_rn(v.z, v.x), __fsub_rn(v.w, v.y));
    } else {
      sx0[t] = 1e30f; sy0[t] = 1e30f; sx1[t] = -1e30f; sy1[t] = -1e30f;
      sa[t] = 0.f;
    }
    __syncthreads();
    const int j = jt * 256 + t;
    if (j >= K_) return;
    float4 v = ((const float4*)boxK)[b * K_ + j];
    const float aj = __fmul_rn(__fsub_rn(v.z, v.x), __fsub_rn(v.w, v.y));
    float mx = 0.f;
    int lim = j - gi0;
    if (lim > 256) lim = 256;
    for (int ii = 0; ii < lim; ++ii) {
      float ltx = fmaxf(sx0[ii], v.x);
      float lty = fmaxf(sy0[ii], v.y);
      float rbx = fminf(sx1[ii], v.z);
      float rby = fminf(sy1[ii], v.w);
      float wx = fmaxf(__fsub_rn(rbx, ltx), 0.f);
      float wy = fmaxf(__fsub_rn(rby, lty), 0.f);
      float inter = __fmul_rn(wx, wy);
      if (inter > 0.f) {
        float uni = __fsub_rn(__fadd_rn(sa[ii], aj), inter);
        mx = fmaxf(mx, __fdiv_rn(inter, uni));
      }
    }
    if (mx > 0.f) atomicMax(&maxiou[b * K_ + j], __float_as_uint(mx));
  } else {
    const int v2 = u - 420;
    const int b = v2 / 1252;
    const int rem = v2 % 1252;
    const int c0 = (rem / 313) * 64;
    const int n0 = (rem % 313) * 64;
    float* T = (float*)arena;  // [64][65]
    const int nl = t & 63, wq = t >> 6;
#pragma unroll
    for (int r = 0; r < 16; ++r) {
      const int cl = r * 4 + wq;
      const int n = n0 + nl;
      T[nl * 65 + cl] =
          (n < N_) ? feat[((size_t)(b * C_ + c0 + cl)) * N_ + n] : 0.f;
    }
    __syncthreads();
    const int nn = n0 + (t >> 2);
    if (nn >= N_) return;
    const int r = rnk[b * N_ + nn];
    if (r >= K_) return;
    const int cseg = (t & 3) * 16;
    unsigned short hb[16], lb[16];
#pragma unroll
    for (int i = 0; i < 16; ++i) {
      const float v = T[(t >> 2) * 65 + cseg + i];
      const unsigned short hh = f2bf(v);
      hb[i] = hh;
      lb[i] = f2bf(__fsub_rn(v, bf2f(hh)));
    }
    const size_t base = (size_t)(b * K_ + r) * C_ + c0 + cseg;
    *(uint4*)&Xhi[base] = *(const uint4*)&hb[0];
    *(uint4*)&Xhi[base + 8] = *(const uint4*)&hb[8];
    *(uint4*)&Xlo[base] = *(const uint4*)&lb[0];
    *(uint4*)&Xlo[base + 8] = *(const uint4*)&lb[8];
  }
}

// ---------------------------------------------------------------------------
// K5: all 6 MLP layers with activations resident in LDS (48 rows/block,
// 209 blocks = 1 balanced block/CU), 512 threads = 8 waves (wave w owns o in
// [w*32, w*32+32), mi=3 row tiles), then fused final GEMV+softmax+mask.
// W loads: packed layout, base + lane*16B (coalesced 1KB txns).
__global__ __launch_bounds__(512) void k_mlp6(
    const unsigned short* __restrict__ Whi, const unsigned short* __restrict__ Wlo,
    const float* __restrict__ bias, const float* __restrict__ Wf,
    const float* __restrict__ bf, const unsigned* __restrict__ maxiou,
    const unsigned short* __restrict__ Xhi, const unsigned short* __restrict__ Xlo,
    float* __restrict__ out_loc) {
  __shared__ unsigned short act_hi[MLPROWS_ * AST_];
  __shared__ unsigned short act_lo[MLPROWS_ * AST_];
  __shared__ float swf[768];
  const int t = threadIdx.x;
  const int m0 = blockIdx.x * MLPROWS_;

  // stage initial activations (coalesced): unit = (row, 16-col seg)
  for (int idx = t; idx < MLPROWS_ * 16; idx += 512) {
    const int r = idx >> 4;
    const int cs = (idx & 15) * 16;
    const size_t g = (size_t)(m0 + r) * C_ + cs;
    *(uint4*)&act_hi[r * AST_ + cs] = *(const uint4*)&Xhi[g];
    *(uint4*)&act_hi[r * AST_ + cs + 8] = *(const uint4*)&Xhi[g + 8];
    *(uint4*)&act_lo[r * AST_ + cs] = *(const uint4*)&Xlo[g];
    *(uint4*)&act_lo[r * AST_ + cs + 8] = *(const uint4*)&Xlo[g + 8];
  }
  for (int i = t; i < 768; i += 512) swf[i] = Wf[i];
  __syncthreads();

  const int lane = t & 63;
  const int w = t >> 6;            // wave id -> o base w*32
  const int quad = lane >> 4, l15 = lane & 15;

  for (int l = 0; l < 6; ++l) {
    // packed W (shorts): (l*8+w)*8192 + ks*1024 + oi*512 + lane*8
    const size_t wbase = (size_t)(l * 8 + w) * 8192 + (size_t)lane * 8;
    f32x4 acc[3][2];
#pragma unroll
    for (int mi = 0; mi < 3; ++mi)
#pragma unroll
      for (int oi = 0; oi < 2; ++oi) acc[mi][oi] = (f32x4)0.f;
    uint4 nwh[2], nwl[2];
#pragma unroll
    for (int oi = 0; oi < 2; ++oi) {
      nwh[oi] = *(const uint4*)&Whi[wbase + oi * 512];
      nwl[oi] = *(const uint4*)&Wlo[wbase + oi * 512];
    }
#pragma unroll
    for (int ks = 0; ks < 8; ++ks) {
      bf16x8 wh[2], wl[2];
#pragma unroll
      for (int oi = 0; oi < 2; ++oi) { wh[oi] = as_bf(nwh[oi]); wl[oi] = as_bf(nwl[oi]); }
      if (ks < 7) {
        const size_t nb = wbase + (size_t)(ks + 1) * 1024;
#pragma unroll
        for (int oi = 0; oi < 2; ++oi) {
          nwh[oi] = *(const uint4*)&Whi[nb + oi * 512];
          nwl[oi] = *(const uint4*)&Wlo[nb + oi * 512];
        }
      }
      bf16x8 Ah[3], Al[3];
#pragma unroll
      for (int mi = 0; mi < 3; ++mi) {
        const int off = (mi * 16 + l15) * AST_ + ks * 32 + quad * 8;
        Ah[mi] = *(const bf16x8*)&act_hi[off];
        Al[mi] = *(const bf16x8*)&act_lo[off];
      }
#pragma unroll
      for (int mi = 0; mi < 3; ++mi)
#pragma unroll
        for (int oi = 0; oi < 2; ++oi) {
          acc[mi][oi] = __builtin_amdgcn_mfma_f32_16x16x32_bf16(Ah[mi], wh[oi], acc[mi][oi], 0, 0, 0);
          acc[mi][oi] = __builtin_amdgcn_mfma_f32_16x16x32_bf16(Ah[mi], wl[oi], acc[mi][oi], 0, 0, 0);
          acc[mi][oi] = __builtin_amdgcn_mfma_f32_16x16x32_bf16(Al[mi], wh[oi], acc[mi][oi], 0, 0, 0);
        }
    }
    __syncthreads();  // all A reads done before overwrite
#pragma unroll
    for (int oi = 0; oi < 2; ++oi) {
      const int col = w * 32 + oi * 16 + l15;
      const float bb = bias[l * C_ + col];
#pragma unroll
      for (int mi = 0; mi < 3; ++mi)
#pragma unroll
        for (int r = 0; r < 4; ++r) {
          float y = acc[mi][oi][r] + bb;
          y = fmaxf(y, 0.2f * y);
          const int row = mi * 16 + quad * 4 + r;
          const unsigned short hh = f2bf(y);
          act_hi[row * AST_ + col] = hh;
          act_lo[row * AST_ + col] = f2bf(__fsub_rn(y, bf2f(hh)));
        }
    }
    __syncthreads();
  }

  // fused final: 16 threads per row, partial GEMV + shuffle reduce (16-wide)
  for (int idx = t; idx < MLPROWS_ * 16; idx += 512) {
    const int r = idx >> 4;
    const int part = idx & 15;
    const int m = m0 + r;
    float a0 = 0.f, a1 = 0.f, a2 = 0.f;
    for (int c = part * 16; c < part * 16 + 16; c += 2) {
      const unsigned hv = *(const unsigned*)&act_hi[r * AST_ + c];
      const unsigned lv = *(const unsigned*)&act_lo[r * AST_ + c];
      const float x0 = __uint_as_float((hv & 0xffffu) << 16) +
                       __uint_as_float((lv & 0xffffu) << 16);
      const float x1 = __uint_as_float(hv & 0xffff0000u) +
                       __uint_as_float(lv & 0xffff0000u);
      a0 += swf[c] * x0 + swf[c + 1] * x1;
      a1 += swf[256 + c] * x0 + swf[256 + c + 1] * x1;
      a2 += swf[512 + c] * x0 + swf[512 + c + 1] * x1;
    }
#pragma unroll
    for (int off = 1; off < 16; off <<= 1) {
      a0 += __shfl_xor(a0, off);
      a1 += __shfl_xor(a1, off);
      a2 += __shfl_xor(a2, off);
    }
    if (part == 0 && m < M_) {
      float b0 = a0 + bf[0], b1 = a1 + bf[1], b2 = a2 + bf[2];
      const float mxv = fmaxf(b0, fmaxf(b1, b2));
      const float e0 = expf(b0 - mxv);
      const float e1 = expf(b1 - mxv);
      const float e2 = expf(b2 - mxv);
      const float inv = 1.f / (e0 + e1 + e2);
      const float miou = __uint_as_float(maxiou[m]);
      float loc = 0.f;
      if (miou < 0.4f) loc += e0;
      if (miou < 0.6f) loc += e1;
      if (miou < 0.8f) loc += e2;
      out_loc[m] = loc * inv;
    }
  }
}

// ---------------------------------------------------------------------------
extern "C" void kernel_launch(void* const* d_in, const int* in_sizes, int n_in,
                              void* d_out, int out_size, void* d_ws, size_t ws_size,
                              hipStream_t stream) {
  const float* box   = (const float*)d_in[0];
  const float* score = (const float*)d_in[1];
  const float* feat  = (const float*)d_in[2];
  const float* W     = (const float*)d_in[3];
  const float* bias  = (const float*)d_in[4];
  const float* Wf    = (const float*)d_in[5];
  const float* bf    = (const float*)d_in[6];

  float* out = (float*)d_out;
  float* out_loc  = out;
  float* out_keep = out + M_;

  char* ws = (char*)d_ws;
  int*            keep_i = (int*)(ws + 0);
  float*          boxK   = (float*)(ws + 40960);
  unsigned*       maxiou = (unsigned*)(ws + 201216);
  unsigned short* Whi    = (unsigned short*)(ws + 241664);
  unsigned short* Wlo    = (unsigned short*)(ws + 1028096);
  unsigned short* XtA_hi = (unsigned short*)(ws + 1814528);
  unsigned short* XtA_lo = (unsigned short*)(ws + 6991872);
  int*                rnk    = (int*)(ws + 12169216);
  unsigned long long* ck     = (unsigned long long*)(ws + 12329216);
  int*                cnt2   = (int*)(ws + 12415232);
  int*                nc     = (int*)(ws + 12458240);
  int*                ticket = (int*)(ws + 12458496);  // 42 ints

  k_prep<<<235, 256, 0, stream>>>(W, Whi, Wlo, nc, cnt2, ticket);
  k_selcomp<<<dim3(79, B_), 256, 0, stream>>>(score, nc, ck, rnk);
  k_rank2<<<dim3(RT_, RCH_, B_), 256, 0, stream>>>(nc, ck, cnt2, ticket, box,
                                                   keep_i, out_keep, rnk, boxK,
                                                   maxiou);
  k_ioug<<<2924, 256, 0, stream>>>(boxK, maxiou, rnk, feat, XtA_hi, XtA_lo);
  k_mlp6<<<MLPBLK_, 512, 0, stream>>>(Whi, Wlo, bias, Wf, bf, maxiou,
                                      XtA_hi, XtA_lo, out_loc);
}

// Round 12
// 186.052 us; speedup vs baseline: 1.2514x; 1.2514x over previous
//
#include <hip/hip_runtime.h>

// Problem constants
#define B_  2
#define N_  20000
#define C_  256
#define K_  5000
#define M_  (B_ * K_)     // 10000
#define CAP_ 5376         // survivor capacity per batch
#define NBIN_ 2048
#define AST_ 264          // act LDS row stride (shorts): 16B-aligned
#define RT_  21           // CAP_/256 j-tiles
#define RCH_ 7            // rank chunk count
#define RCT_ 3            // tiles per rank chunk

typedef __attribute__((ext_vector_type(8))) short bf16x8;
typedef __attribute__((ext_vector_type(4))) float f32x4;
typedef __attribute__((ext_vector_type(2))) unsigned long long ull2;

__device__ __forceinline__ unsigned short f2bf(float x) {
  unsigned u = __float_as_uint(x);
  return (unsigned short)((u + 0x7fffu + ((u >> 16) & 1u)) >> 16);
}
__device__ __forceinline__ float bf2f(unsigned short h) {
  return __uint_as_float(((unsigned)h) << 16);
}
__device__ __forceinline__ unsigned fkey(float f) {
  unsigned u = __float_as_uint(f);
  return (u & 0x80000000u) ? ~u : (u | 0x80000000u);
}
// monotone linear bin; only hist/compact CONSISTENCY matters (upward-closed set)
__device__ __forceinline__ int binof(float s) {
  int b = (int)(s * 2048.0f);
  return b < 0 ? 0 : (b > 2047 ? 2047 : b);
}
__device__ __forceinline__ bf16x8 as_bf(uint4 v) {
  union { uint4 u; bf16x8 b; } c; c.u = v; return c.b;
}

// ---------------------------------------------------------------------------
// K1: W f32 -> bf16 (RNE), PRE-PACKED into per-wave MFMA fragment order for
// the 8-wave k_mlp6:  Wp[l][w8][ks][oi2][lane][j]  (j=0..7 shorts)
// holding W[o = w*32 + oi*16 + (lane&15)][k = ks*32 + (lane>>4)*8 + j].
// A wave's W load is then base + lane*16B -> one coalesced 1KB txn.
// Also zeros nc and cnt2.  (Pure-bf16 MLP: no lo residual arrays.)
__global__ __launch_bounds__(256) void k_prep(const float* __restrict__ W,
                                              unsigned short* __restrict__ Whi,
                                              int* __restrict__ nc,
                                              int* __restrict__ cnt2) {
  const int u = blockIdx.x;
  const int t = threadIdx.x;
  if (u >= 192) {
    if (u == 234) { if (t < B_) nc[t] = 0; return; }
    const int i = (u - 192) * 256 + t;
    if (i < B_ * CAP_) cnt2[i] = 0;
    return;
  }
  const int idx = u * 256 + t;  // 0..49151 = [l][w][ks][oi][lane]
  const int lane = idx & 63;
  const int oi = (idx >> 6) & 1;
  const int ks = (idx >> 7) & 7;
  const int w = (idx >> 10) & 7;
  const int l = idx >> 13;
  const int o = w * 32 + oi * 16 + (lane & 15);
  const int k0 = ks * 32 + (lane >> 4) * 8;
  const float* src = W + ((size_t)(l * C_ + o)) * C_ + k0;
  float4 w0 = *(const float4*)&src[0];
  float4 w1 = *(const float4*)&src[4];
  const float wv[8] = {w0.x, w0.y, w0.z, w0.w, w1.x, w1.y, w1.z, w1.w};
  unsigned short hs[8];
#pragma unroll
  for (int q = 0; q < 8; ++q) hs[q] = f2bf(wv[q]);
  *(uint4*)&Whi[(size_t)idx * 8] = *(const uint4*)&hs[0];
}

// ---------------------------------------------------------------------------
// K2: per-block LDS histogram + select threshold bin + compact survivors.
__global__ __launch_bounds__(256) void k_selcomp(const float* __restrict__ score,
                                                 int* __restrict__ nc,
                                                 unsigned long long* __restrict__ ck,
                                                 int* __restrict__ rnk) {
  const int b = blockIdx.y;
  const float* s = score + b * N_;
  __shared__ int h[NBIN_];
  __shared__ int chs[256];
  __shared__ int res[1];
  const int t = threadIdx.x;
  for (int i = t; i < NBIN_; i += 256) h[i] = 0;
  __syncthreads();
  for (int i = t; i < N_; i += 256) atomicAdd(&h[binof(s[i])], 1);
  __syncthreads();
  int sum = 0;
#pragma unroll
  for (int j = 0; j < 8; ++j) sum += h[t * 8 + j];
  chs[t] = sum;
  __syncthreads();
  for (int off = 1; off < 256; off <<= 1) {
    int v = chs[t] + ((t + off < 256) ? chs[t + off] : 0);
    __syncthreads();
    chs[t] = v;
    __syncthreads();
  }
  const int above = (t + 1 < 256) ? chs[t + 1] : 0;
  if (above < K_ && K_ <= chs[t]) {
    int acc = above;
    for (int i = 7; i >= 0; --i) {
      const int bin = t * 8 + i;
      if (acc + h[bin] >= K_) { res[0] = bin; break; }
      acc += h[bin];
    }
  }
  __syncthreads();
  const int selB = res[0];
  const int n = blockIdx.x * 256 + t;
  if (n < N_) {
    rnk[b * N_ + n] = K_;
    const float sv = s[n];
    if (binof(sv) >= selB) {
      const int pos = atomicAdd(&nc[b], 1);
      if (pos < CAP_)
        ck[b * CAP_ + pos] =
            ((unsigned long long)fkey(sv) << 32) | (unsigned)(N_ - 1 - n);
    }
  }
}

// ---------------------------------------------------------------------------
// K3: partial exact rank among survivors (chunked for occupancy: 294 blocks).
__global__ __launch_bounds__(256) void k_rank2(const int* __restrict__ nc,
                                               const unsigned long long* __restrict__ ck,
                                               int* __restrict__ cnt2) {
  const int b = blockIdx.z;
  int S = nc[b]; if (S > CAP_) S = CAP_;
  __shared__ unsigned long long sk[256];
  const int t = threadIdx.x;
  const int j = blockIdx.x * 256 + t;
  const unsigned long long* kb = ck + b * CAP_;
  const unsigned long long myk = (j < S) ? kb[j] : 0ULL;
  int c = 0;
  const int nt = (S + 255) >> 8;
  int t0 = blockIdx.y * RCT_, t1 = t0 + RCT_;
  if (t1 > nt) t1 = nt;
  for (int tt = t0; tt < t1; ++tt) {
    const int gi = tt * 256 + t;
    unsigned long long kk = (gi < S) ? kb[gi] : 0ULL;
    __syncthreads();
    sk[t] = kk;
    __syncthreads();
#pragma unroll 8
    for (int ii = 0; ii < 256; ii += 2) {
      ull2 v = *(const ull2*)&sk[ii];
      c += (int)(v.x > myk) + (int)(v.y > myk);
    }
  }
  if (j < S && c > 0) atomicAdd(&cnt2[b * CAP_ + j], c);
}

// ---------------------------------------------------------------------------
// K4: scatter keep/out_keep/rnk/boxK/maxiou from final ranks.
__global__ __launch_bounds__(256) void k_scatter2(const int* __restrict__ nc,
                                                  const unsigned long long* __restrict__ ck,
                                                  const int* __restrict__ cnt2,
                                                  const float* __restrict__ box,
                                                  int* __restrict__ keep_i,
                                                  float* __restrict__ out_keep,
                                                  int* __restrict__ rnk,
                                                  float* __restrict__ boxK,
                                                  unsigned* __restrict__ maxiou) {
  const int b = blockIdx.y;
  int S = nc[b]; if (S > CAP_) S = CAP_;
  const int j = blockIdx.x * 256 + threadIdx.x;
  if (j >= S) return;
  const int c = cnt2[b * CAP_ + j];
  if (c >= K_) return;
  const int n = N_ - 1 - (int)(ck[b * CAP_ + j] & 0xffffffffu);
  keep_i[b * K_ + c] = n;
  out_keep[b * K_ + c] = (float)n;
  rnk[b * N_ + n] = c;
  const float* bb = box + (size_t)b * 4 * N_;
  float4 v;
  v.x = bb[n]; v.y = bb[N_ + n]; v.z = bb[2 * N_ + n]; v.w = bb[3 * N_ + n];
  ((float4*)boxK)[b * K_ + c] = v;
  maxiou[b * K_ + c] = 0u;
}

// ---------------------------------------------------------------------------
// K5: iou (420 triangular units) + gather/transpose/bf16 (2504 units).
__global__ __launch_bounds__(256) void k_ioug(const float* __restrict__ boxK,
                                              unsigned* __restrict__ maxiou,
                                              const int* __restrict__ rnk,
                                              const float* __restrict__ feat,
                                              unsigned short* __restrict__ Xhi) {
  __shared__ __align__(16) char arena[16640];
  const int u = blockIdx.x;
  const int t = threadIdx.x;
  if (u < 420) {
    const int b = u / 210;
    const int p = u % 210;
    int jt = 0;
    while ((jt + 1) * (jt + 2) / 2 <= p) ++jt;
    const int it = p - jt * (jt + 1) / 2;
    float* sx0 = (float*)arena;
    float* sy0 = sx0 + 256; float* sx1 = sy0 + 256;
    float* sy1 = sx1 + 256; float* sa = sy1 + 256;
    const int gi0 = it * 256;
    const int gl = gi0 + t;
    if (gl < K_) {
      float4 v = ((const float4*)boxK)[b * K_ + gl];
      sx0[t] = v.x; sy0[t] = v.y; sx1[t] = v.z; sy1[t] = v.w;
      sa[t] = __fmul_rn(__fsub_rn(v.z, v.x), __fsub_rn(v.w, v.y));
    } else {
      sx0[t] = 1e30f; sy0[t] = 1e30f; sx1[t] = -1e30f; sy1[t] = -1e30f;
      sa[t] = 0.f;
    }
    __syncthreads();
    const int j = jt * 256 + t;
    if (j >= K_) return;
    float4 v = ((const float4*)boxK)[b * K_ + j];
    const float aj = __fmul_rn(__fsub_rn(v.z, v.x), __fsub_rn(v.w, v.y));
    float mx = 0.f;
    int lim = j - gi0;
    if (lim > 256) lim = 256;
    for (int ii = 0; ii < lim; ++ii) {
      float ltx = fmaxf(sx0[ii], v.x);
      float lty = fmaxf(sy0[ii], v.y);
      float rbx = fminf(sx1[ii], v.z);
      float rby = fminf(sy1[ii], v.w);
      float wx = fmaxf(__fsub_rn(rbx, ltx), 0.f);
      float wy = fmaxf(__fsub_rn(rby, lty), 0.f);
      float inter = __fmul_rn(wx, wy);
      if (inter > 0.f) {
        float uni = __fsub_rn(__fadd_rn(sa[ii], aj), inter);
        mx = fmaxf(mx, __fdiv_rn(inter, uni));
      }
    }
    if (mx > 0.f) atomicMax(&maxiou[b * K_ + j], __float_as_uint(mx));
  } else {
    const int v2 = u - 420;
    const int b = v2 / 1252;
    const int rem = v2 % 1252;
    const int c0 = (rem / 313) * 64;
    const int n0 = (rem % 313) * 64;
    float* T = (float*)arena;  // [64][65]
    const int nl = t & 63, wq = t >> 6;
#pragma unroll
    for (int r = 0; r < 16; ++r) {
      const int cl = r * 4 + wq;
      const int n = n0 + nl;
      T[nl * 65 + cl] =
          (n < N_) ? feat[((size_t)(b * C_ + c0 + cl)) * N_ + n] : 0.f;
    }
    __syncthreads();
    const int nn = n0 + (t >> 2);
    if (nn >= N_) return;
    const int r = rnk[b * N_ + nn];
    if (r >= K_) return;
    const int cseg = (t & 3) * 16;
    unsigned short hb[16];
#pragma unroll
    for (int i = 0; i < 16; ++i)
      hb[i] = f2bf(T[(t >> 2) * 65 + cseg + i]);
    const size_t base = (size_t)(b * K_ + r) * C_ + c0 + cseg;
    *(uint4*)&Xhi[base] = *(const uint4*)&hb[0];
    *(uint4*)&Xhi[base + 8] = *(const uint4*)&hb[8];
  }
}

// ---------------------------------------------------------------------------
// K6: all 6 MLP layers, pure-bf16 operands + f32 MFMA accumulate, activations
// resident in LDS (32 rows/block), 512 threads = 8 waves (wave w owns o in
// [w*32, w*32+32)), then fused final 3-row GEMV + softmax + masked sum.
// W loads: packed layout, base + lane*16B (coalesced 1KB txns).
__global__ __launch_bounds__(512, 2) void k_mlp6(
    const unsigned short* __restrict__ Whi,
    const float* __restrict__ bias, const float* __restrict__ Wf,
    const float* __restrict__ bf, const unsigned* __restrict__ maxiou,
    const unsigned short* __restrict__ Xhi,
    float* __restrict__ out_loc) {
  __shared__ unsigned short act_hi[32 * AST_];
  __shared__ float swf[768];
  const int t = threadIdx.x;
  const int m0 = blockIdx.x * 32;

  // stage initial activations (coalesced): thread = (row t>>4, 16-col seg)
  {
    const int r = t >> 4;
    const int cs = (t & 15) * 16;
    const size_t g = (size_t)(m0 + r) * C_ + cs;
    *(uint4*)&act_hi[r * AST_ + cs] = *(const uint4*)&Xhi[g];
    *(uint4*)&act_hi[r * AST_ + cs + 8] = *(const uint4*)&Xhi[g + 8];
  }
  for (int i = t; i < 768; i += 512) swf[i] = Wf[i];
  __syncthreads();

  const int lane = t & 63;
  const int w = t >> 6;            // wave id -> o base w*32
  const int quad = lane >> 4, l15 = lane & 15;

  for (int l = 0; l < 6; ++l) {
    // packed W (shorts): (l*8+w)*8192 + ks*1024 + oi*512 + lane*8
    const size_t wbase = (size_t)(l * 8 + w) * 8192 + (size_t)lane * 8;
    f32x4 acc[2][2];
#pragma unroll
    for (int mi = 0; mi < 2; ++mi)
#pragma unroll
      for (int oi = 0; oi < 2; ++oi) acc[mi][oi] = (f32x4)0.f;
    uint4 nwh[2];
#pragma unroll
    for (int oi = 0; oi < 2; ++oi)
      nwh[oi] = *(const uint4*)&Whi[wbase + oi * 512];
#pragma unroll
    for (int ks = 0; ks < 8; ++ks) {
      bf16x8 wh[2];
#pragma unroll
      for (int oi = 0; oi < 2; ++oi) wh[oi] = as_bf(nwh[oi]);
      if (ks < 7) {
        const size_t nb = wbase + (size_t)(ks + 1) * 1024;
#pragma unroll
        for (int oi = 0; oi < 2; ++oi)
          nwh[oi] = *(const uint4*)&Whi[nb + oi * 512];
      }
      bf16x8 Ah[2];
#pragma unroll
      for (int mi = 0; mi < 2; ++mi)
        Ah[mi] = *(const bf16x8*)&act_hi[(mi * 16 + l15) * AST_ + ks * 32 + quad * 8];
#pragma unroll
      for (int mi = 0; mi < 2; ++mi)
#pragma unroll
        for (int oi = 0; oi < 2; ++oi)
          acc[mi][oi] = __builtin_amdgcn_mfma_f32_16x16x32_bf16(Ah[mi], wh[oi], acc[mi][oi], 0, 0, 0);
    }
    __syncthreads();  // all A reads done before overwrite
#pragma unroll
    for (int oi = 0; oi < 2; ++oi) {
      const int col = w * 32 + oi * 16 + l15;
      const float bb = bias[l * C_ + col];
#pragma unroll
      for (int mi = 0; mi < 2; ++mi)
#pragma unroll
        for (int r = 0; r < 4; ++r) {
          float y = acc[mi][oi][r] + bb;
          y = fmaxf(y, 0.2f * y);
          act_hi[(mi * 16 + quad * 4 + r) * AST_ + col] = f2bf(y);
        }
    }
    __syncthreads();
  }

  // fused final: 16 threads per row, partial GEMV + shuffle reduce
  const int r = t >> 4;
  const int part = t & 15;
  const int m = m0 + r;
  float a0 = 0.f, a1 = 0.f, a2 = 0.f;
  for (int c = part * 16; c < part * 16 + 16; c += 2) {
    const unsigned hv = *(const unsigned*)&act_hi[r * AST_ + c];
    const float x0 = __uint_as_float((hv & 0xffffu) << 16);
    const float x1 = __uint_as_float(hv & 0xffff0000u);
    a0 += swf[c] * x0 + swf[c + 1] * x1;
    a1 += swf[256 + c] * x0 + swf[256 + c + 1] * x1;
    a2 += swf[512 + c] * x0 + swf[512 + c + 1] * x1;
  }
#pragma unroll
  for (int off = 1; off < 16; off <<= 1) {
    a0 += __shfl_xor(a0, off);
    a1 += __shfl_xor(a1, off);
    a2 += __shfl_xor(a2, off);
  }
  if (part == 0 && m < M_) {
    a0 += bf[0]; a1 += bf[1]; a2 += bf[2];
    const float mxv = fmaxf(a0, fmaxf(a1, a2));
    const float e0 = expf(a0 - mxv);
    const float e1 = expf(a1 - mxv);
    const float e2 = expf(a2 - mxv);
    const float inv = 1.f / (e0 + e1 + e2);
    const float miou = __uint_as_float(maxiou[m]);
    float loc = 0.f;
    if (miou < 0.4f) loc += e0;
    if (miou < 0.6f) loc += e1;
    if (miou < 0.8f) loc += e2;
    out_loc[m] = loc * inv;
  }
}

// ---------------------------------------------------------------------------
extern "C" void kernel_launch(void* const* d_in, const int* in_sizes, int n_in,
                              void* d_out, int out_size, void* d_ws, size_t ws_size,
                              hipStream_t stream) {
  const float* box   = (const float*)d_in[0];
  const float* score = (const float*)d_in[1];
  const float* feat  = (const float*)d_in[2];
  const float* W     = (const float*)d_in[3];
  const float* bias  = (const float*)d_in[4];
  const float* Wf    = (const float*)d_in[5];
  const float* bf    = (const float*)d_in[6];

  float* out = (float*)d_out;
  float* out_loc  = out;
  float* out_keep = out + M_;

  char* ws = (char*)d_ws;
  int*            keep_i = (int*)(ws + 0);
  float*          boxK   = (float*)(ws + 40960);
  unsigned*       maxiou = (unsigned*)(ws + 201216);
  unsigned short* Whi    = (unsigned short*)(ws + 241664);
  unsigned short* XtA_hi = (unsigned short*)(ws + 1814528);
  int*                rnk    = (int*)(ws + 12169216);
  unsigned long long* ck     = (unsigned long long*)(ws + 12329216);
  int*                cnt2   = (int*)(ws + 12415232);
  int*                nc     = (int*)(ws + 12458240);

  k_prep<<<235, 256, 0, stream>>>(W, Whi, nc, cnt2);
  k_selcomp<<<dim3(79, B_), 256, 0, stream>>>(score, nc, ck, rnk);
  k_rank2<<<dim3(RT_, RCH_, B_), 256, 0, stream>>>(nc, ck, cnt2);
  k_scatter2<<<dim3(RT_, B_), 256, 0, stream>>>(nc, ck, cnt2, box, keep_i,
                                                out_keep, rnk, boxK, maxiou);
  k_ioug<<<2924, 256, 0, stream>>>(boxK, maxiou, rnk, feat, XtA_hi);
  k_mlp6<<<313, 512, 0, stream>>>(Whi, bias, Wf, bf, maxiou, XtA_hi, out_loc);
}